// Round 1
// baseline (2037.844 us; speedup 1.0000x reference)
//
#include <hip/hip_runtime.h>

#define NN 50000
#define NE 800000
#define D 128

// ---------------- GEMM: O[M x D] = X[M x D] @ W[D x D] ----------------
// 64-row tile, 256 threads, per-thread 4 rows x 8 cols.
// xs padded to stride 130 (conflict-free a-reads); W staged in 32-row k-chunks
// to keep LDS at 49.3 KB -> 3 blocks/CU.

__global__ __launch_bounds__(256) void gemm_plain(
    const float* __restrict__ X, const float* __restrict__ W,
    float* __restrict__ O, int M) {
  __shared__ float xs[64 * 130];
  __shared__ float ws[32 * 128];
  const int tid = threadIdx.x;
  const int r0 = blockIdx.x * 64;
  for (int i = tid; i < 64 * 64; i += 256) {
    int row = i >> 6, kh = i & 63;
    float2 v = make_float2(0.f, 0.f);
    int gr = r0 + row;
    if (gr < M) v = *(const float2*)&X[(size_t)gr * D + kh * 2];
    *(float2*)&xs[row * 130 + kh * 2] = v;
  }
  const int tx = tid & 15, ty = tid >> 4;
  float acc[4][8];
#pragma unroll
  for (int i = 0; i < 4; i++)
#pragma unroll
    for (int j = 0; j < 8; j++) acc[i][j] = 0.f;

  for (int kc = 0; kc < 4; kc++) {
    __syncthreads();
    for (int i = tid; i < 32 * 32; i += 256) {
      ((float4*)ws)[i] = ((const float4*)(W + kc * 32 * D))[i];
    }
    __syncthreads();
#pragma unroll 4
    for (int k2 = 0; k2 < 32; k2++) {
      const int k = kc * 32 + k2;
      float a[4];
#pragma unroll
      for (int j = 0; j < 4; j++) a[j] = xs[(ty * 4 + j) * 130 + k];
      float4 b0 = *(const float4*)&ws[k2 * 128 + tx * 8];
      float4 b1 = *(const float4*)&ws[k2 * 128 + tx * 8 + 4];
      float b[8] = {b0.x, b0.y, b0.z, b0.w, b1.x, b1.y, b1.z, b1.w};
#pragma unroll
      for (int i = 0; i < 4; i++)
#pragma unroll
        for (int j = 0; j < 8; j++) acc[i][j] += a[i] * b[j];
    }
  }
#pragma unroll
  for (int i = 0; i < 4; i++) {
    int gr = r0 + ty * 4 + i;
    if (gr < M) {
      float4 o0 = make_float4(acc[i][0], acc[i][1], acc[i][2], acc[i][3]);
      float4 o1 = make_float4(acc[i][4], acc[i][5], acc[i][6], acc[i][7]);
      *(float4*)&O[(size_t)gr * D + tx * 8] = o0;
      *(float4*)&O[(size_t)gr * D + tx * 8 + 4] = o1;
    }
  }
}

// In-place: IO = prelu(IO @ W + bias). Each block reads/writes only its own rows.
__global__ __launch_bounds__(256) void gemm_epi(
    float* __restrict__ IO, const float* __restrict__ W,
    const float* __restrict__ bias, const float* __restrict__ pa, int M) {
  __shared__ float xs[64 * 130];
  __shared__ float ws[32 * 128];
  const int tid = threadIdx.x;
  const int r0 = blockIdx.x * 64;
  for (int i = tid; i < 64 * 64; i += 256) {
    int row = i >> 6, kh = i & 63;
    float2 v = make_float2(0.f, 0.f);
    int gr = r0 + row;
    if (gr < M) v = *(const float2*)&IO[(size_t)gr * D + kh * 2];
    *(float2*)&xs[row * 130 + kh * 2] = v;
  }
  const int tx = tid & 15, ty = tid >> 4;
  float bv[8], av[8];
#pragma unroll
  for (int j = 0; j < 8; j++) {
    bv[j] = bias[tx * 8 + j];
    av[j] = pa[tx * 8 + j];
  }
  float acc[4][8];
#pragma unroll
  for (int i = 0; i < 4; i++)
#pragma unroll
    for (int j = 0; j < 8; j++) acc[i][j] = 0.f;

  for (int kc = 0; kc < 4; kc++) {
    __syncthreads();
    for (int i = tid; i < 32 * 32; i += 256) {
      ((float4*)ws)[i] = ((const float4*)(W + kc * 32 * D))[i];
    }
    __syncthreads();
#pragma unroll 4
    for (int k2 = 0; k2 < 32; k2++) {
      const int k = kc * 32 + k2;
      float a[4];
#pragma unroll
      for (int j = 0; j < 4; j++) a[j] = xs[(ty * 4 + j) * 130 + k];
      float4 b0 = *(const float4*)&ws[k2 * 128 + tx * 8];
      float4 b1 = *(const float4*)&ws[k2 * 128 + tx * 8 + 4];
      float b[8] = {b0.x, b0.y, b0.z, b0.w, b1.x, b1.y, b1.z, b1.w};
#pragma unroll
      for (int i = 0; i < 4; i++)
#pragma unroll
        for (int j = 0; j < 8; j++) acc[i][j] += a[i] * b[j];
    }
  }
#pragma unroll
  for (int i = 0; i < 4; i++) {
    int gr = r0 + ty * 4 + i;
    if (gr < M) {
#pragma unroll
      for (int j = 0; j < 8; j++) {
        float v = acc[i][j] + bv[j];
        acc[i][j] = v > 0.f ? v : av[j] * v;
      }
      float4 o0 = make_float4(acc[i][0], acc[i][1], acc[i][2], acc[i][3]);
      float4 o1 = make_float4(acc[i][4], acc[i][5], acc[i][6], acc[i][7]);
      *(float4*)&IO[(size_t)gr * D + tx * 8] = o0;
      *(float4*)&IO[(size_t)gr * D + tx * 8 + 4] = o1;
    }
  }
}

// ---------------- degree / CSR build ----------------

__global__ __launch_bounds__(256) void init_k(float* __restrict__ degw,
                                              int* __restrict__ cnt, int n) {
  int i = blockIdx.x * 256 + threadIdx.x;
  if (i < n) { degw[i] = 1.0f; cnt[i] = 0; }
}

__global__ __launch_bounds__(256) void count_k(const int* __restrict__ dst,
                                               const float* __restrict__ ew,
                                               float* __restrict__ degw,
                                               int* __restrict__ cnt, int E) {
  int e = blockIdx.x * 256 + threadIdx.x;
  if (e < E) {
    int d = dst[e];
    atomicAdd(&degw[d], ew[e]);
    atomicAdd(&cnt[d], 1);
  }
}

__global__ __launch_bounds__(256) void dinv_k(const float* __restrict__ degw,
                                              float* __restrict__ dinv, int n) {
  int i = blockIdx.x * 256 + threadIdx.x;
  if (i < n) dinv[i] = rsqrtf(degw[i]);  // degw >= 1 always (self loop)
}

// single-block exclusive scan of cnt -> offs, cursor
__global__ __launch_bounds__(256) void scan_k(const int* __restrict__ cnt,
                                              int* __restrict__ offs,
                                              int* __restrict__ cursor, int n) {
  __shared__ int sm[256];
  const int tid = threadIdx.x;
  const int chunk = (n + 255) >> 8;
  const int lo = tid * chunk;
  const int hi = min(lo + chunk, n);
  int s = 0;
  for (int i = lo; i < hi; i++) s += cnt[i];
  sm[tid] = s;
  __syncthreads();
  for (int off = 1; off < 256; off <<= 1) {
    int v = (tid >= off) ? sm[tid - off] : 0;
    __syncthreads();
    sm[tid] += v;
    __syncthreads();
  }
  int run = sm[tid] - s;  // exclusive prefix
  for (int i = lo; i < hi; i++) {
    offs[i] = run;
    cursor[i] = run;
    run += cnt[i];
  }
}

// fill CSR entries: ee[pos] = (src, norm_bits)
__global__ __launch_bounds__(256) void fill_k(const int* __restrict__ src,
                                              const int* __restrict__ dst,
                                              const float* __restrict__ ew,
                                              const float* __restrict__ dinv,
                                              int* __restrict__ cursor,
                                              int2* __restrict__ ee, int E) {
  int e = blockIdx.x * 256 + threadIdx.x;
  if (e < E) {
    int s = src[e], d = dst[e];
    float w = ew[e] * dinv[s] * dinv[d];
    int pos = atomicAdd(&cursor[d], 1);
    ee[pos] = make_int2(s, __float_as_int(w));
  }
}

// ---------------- aggregation: wave per node, gather over in-edges ----------------
// out[i] = sum_e norm_e * H[src_e] + dinv[i]^2 * H[i]  (+ bias, prelu if EPI)
template <int EPI>
__global__ __launch_bounds__(256) void gather_k(
    const float* __restrict__ H, const int* __restrict__ offs,
    const int* __restrict__ cnt, const int2* __restrict__ ee,
    const float* __restrict__ dinv, const float* __restrict__ bias,
    const float* __restrict__ pa, float* __restrict__ out, int n) {
  int g = blockIdx.x * 256 + threadIdx.x;
  int wid = g >> 6;
  int lane = g & 63;
  if (wid >= n) return;
  const int st = offs[wid];
  const int len = cnt[wid];
  const int c = lane * 2;
  float ax = 0.f, ay = 0.f;
  for (int j = 0; j < len; j++) {
    int2 p = ee[st + j];
    float w = __int_as_float(p.y);
    float2 v = *(const float2*)&H[(size_t)p.x * D + c];
    ax += w * v.x;
    ay += w * v.y;
  }
  float dv = dinv[wid];
  float d2 = dv * dv;
  float2 h = *(const float2*)&H[(size_t)wid * D + c];
  ax += d2 * h.x;
  ay += d2 * h.y;
  if (EPI) {
    ax += bias[c];
    ay += bias[c + 1];
    ax = ax > 0.f ? ax : pa[c] * ax;
    ay = ay > 0.f ? ay : pa[c + 1] * ay;
  }
  *(float2*)&out[(size_t)wid * D + c] = make_float2(ax, ay);
}

// ---------------- launch ----------------

extern "C" void kernel_launch(void* const* d_in, const int* in_sizes, int n_in,
                              void* d_out, int out_size, void* d_ws, size_t ws_size,
                              hipStream_t stream) {
  const float* x = (const float*)d_in[0];
  const int* ei = (const int*)d_in[1];       // [4][2][NE] int32
  const float* ew = (const float*)d_in[2];   // [4][NE]
  const float* W0 = (const float*)d_in[3];
  const float* b0 = (const float*)d_in[4];
  const float* W1 = (const float*)d_in[5];
  const float* b1 = (const float*)d_in[6];
  const float* pa = (const float*)d_in[7];
  float* out = (float*)d_out;                // [4][NN][D]

  float* H0 = (float*)d_ws;                  // 6.4M floats
  float* Z = H0 + (size_t)NN * D;            // 6.4M floats
  float* degw = Z + (size_t)NN * D;          // 50k
  float* dinv = degw + NN;                   // 50k
  int* cnt = (int*)(dinv + NN);              // 50k
  int* offs = cnt + NN;                      // 50k
  int* cursor = offs + NN;                   // 50k
  int2* ee = (int2*)(cursor + NN);           // 800k int2

  const int gGemm = (NN + 63) / 64;          // 782
  const int gNode = (NN + 255) / 256;        // 196
  const int gEdge = (NE + 255) / 256;        // 3125
  const int gGather = (NN * 64 + 255) / 256; // 12500

  // H0 = x @ W0 (shared across all scales)
  gemm_plain<<<gGemm, 256, 0, stream>>>(x, W0, H0, NN);

  for (int t = 0; t < 4; t++) {
    const int* src = ei + (size_t)t * 2 * NE;
    const int* dst = src + NE;
    const float* ewt = ew + (size_t)t * NE;
    float* outT = out + (size_t)t * NN * D;

    init_k<<<gNode, 256, 0, stream>>>(degw, cnt, NN);
    count_k<<<gEdge, 256, 0, stream>>>(dst, ewt, degw, cnt, NE);
    dinv_k<<<gNode, 256, 0, stream>>>(degw, dinv, NN);
    scan_k<<<1, 256, 0, stream>>>(cnt, offs, cursor, NN);
    fill_k<<<gEdge, 256, 0, stream>>>(src, dst, ewt, dinv, cursor, ee, NE);

    // layer 1: Z = prelu(Agg(H0) + b0)
    gather_k<1><<<gGather, 256, 0, stream>>>(H0, offs, cnt, ee, dinv, b0, pa, Z, NN);
    // layer 2: outT = Agg(Z); then outT = prelu(outT @ W1 + b1) in place
    gather_k<0><<<gGather, 256, 0, stream>>>(Z, offs, cnt, ee, dinv, nullptr, nullptr, outT, NN);
    gemm_epi<<<gGemm, 256, 0, stream>>>(outT, W1, b1, pa, NN);
  }
}

// Round 2
// 1359.241 us; speedup vs baseline: 1.4993x; 1.4993x over previous
//
#include <hip/hip_runtime.h>

#define NN 50000
#define NE 800000
#define D 128
#define SCAN_BLOCKS 196  // ceil(50000/256)

// ---------------- GEMM: O[M x D] = X[M x D] @ W[D x D] ----------------
// 64-row tile, 256 threads, per-thread 4 rows x 8 cols.
// xs padded to stride 130 (conflict-free a-reads); W staged in 32-row k-chunks
// to keep LDS at 49.3 KB -> 3 blocks/CU.

__global__ __launch_bounds__(256) void gemm_plain(
    const float* __restrict__ X, const float* __restrict__ W,
    float* __restrict__ O, int M) {
  __shared__ float xs[64 * 130];
  __shared__ float ws[32 * 128];
  const int tid = threadIdx.x;
  const int r0 = blockIdx.x * 64;
  for (int i = tid; i < 64 * 64; i += 256) {
    int row = i >> 6, kh = i & 63;
    float2 v = make_float2(0.f, 0.f);
    int gr = r0 + row;
    if (gr < M) v = *(const float2*)&X[(size_t)gr * D + kh * 2];
    *(float2*)&xs[row * 130 + kh * 2] = v;
  }
  const int tx = tid & 15, ty = tid >> 4;
  float acc[4][8];
#pragma unroll
  for (int i = 0; i < 4; i++)
#pragma unroll
    for (int j = 0; j < 8; j++) acc[i][j] = 0.f;

  for (int kc = 0; kc < 4; kc++) {
    __syncthreads();
    for (int i = tid; i < 32 * 32; i += 256) {
      ((float4*)ws)[i] = ((const float4*)(W + kc * 32 * D))[i];
    }
    __syncthreads();
#pragma unroll 4
    for (int k2 = 0; k2 < 32; k2++) {
      const int k = kc * 32 + k2;
      float a[4];
#pragma unroll
      for (int j = 0; j < 4; j++) a[j] = xs[(ty * 4 + j) * 130 + k];
      float4 b0 = *(const float4*)&ws[k2 * 128 + tx * 8];
      float4 b1 = *(const float4*)&ws[k2 * 128 + tx * 8 + 4];
      float b[8] = {b0.x, b0.y, b0.z, b0.w, b1.x, b1.y, b1.z, b1.w};
#pragma unroll
      for (int i = 0; i < 4; i++)
#pragma unroll
        for (int j = 0; j < 8; j++) acc[i][j] += a[i] * b[j];
    }
  }
#pragma unroll
  for (int i = 0; i < 4; i++) {
    int gr = r0 + ty * 4 + i;
    if (gr < M) {
      float4 o0 = make_float4(acc[i][0], acc[i][1], acc[i][2], acc[i][3]);
      float4 o1 = make_float4(acc[i][4], acc[i][5], acc[i][6], acc[i][7]);
      *(float4*)&O[(size_t)gr * D + tx * 8] = o0;
      *(float4*)&O[(size_t)gr * D + tx * 8 + 4] = o1;
    }
  }
}

// In-place: IO = prelu(IO @ W + bias). Each block reads/writes only its own rows.
__global__ __launch_bounds__(256) void gemm_epi(
    float* __restrict__ IO, const float* __restrict__ W,
    const float* __restrict__ bias, const float* __restrict__ pa, int M) {
  __shared__ float xs[64 * 130];
  __shared__ float ws[32 * 128];
  const int tid = threadIdx.x;
  const int r0 = blockIdx.x * 64;
  for (int i = tid; i < 64 * 64; i += 256) {
    int row = i >> 6, kh = i & 63;
    float2 v = make_float2(0.f, 0.f);
    int gr = r0 + row;
    if (gr < M) v = *(const float2*)&IO[(size_t)gr * D + kh * 2];
    *(float2*)&xs[row * 130 + kh * 2] = v;
  }
  const int tx = tid & 15, ty = tid >> 4;
  float bv[8], av[8];
#pragma unroll
  for (int j = 0; j < 8; j++) {
    bv[j] = bias[tx * 8 + j];
    av[j] = pa[tx * 8 + j];
  }
  float acc[4][8];
#pragma unroll
  for (int i = 0; i < 4; i++)
#pragma unroll
    for (int j = 0; j < 8; j++) acc[i][j] = 0.f;

  for (int kc = 0; kc < 4; kc++) {
    __syncthreads();
    for (int i = tid; i < 32 * 32; i += 256) {
      ((float4*)ws)[i] = ((const float4*)(W + kc * 32 * D))[i];
    }
    __syncthreads();
#pragma unroll 4
    for (int k2 = 0; k2 < 32; k2++) {
      const int k = kc * 32 + k2;
      float a[4];
#pragma unroll
      for (int j = 0; j < 4; j++) a[j] = xs[(ty * 4 + j) * 130 + k];
      float4 b0 = *(const float4*)&ws[k2 * 128 + tx * 8];
      float4 b1 = *(const float4*)&ws[k2 * 128 + tx * 8 + 4];
      float b[8] = {b0.x, b0.y, b0.z, b0.w, b1.x, b1.y, b1.z, b1.w};
#pragma unroll
      for (int i = 0; i < 4; i++)
#pragma unroll
        for (int j = 0; j < 8; j++) acc[i][j] += a[i] * b[j];
    }
  }
#pragma unroll
  for (int i = 0; i < 4; i++) {
    int gr = r0 + ty * 4 + i;
    if (gr < M) {
#pragma unroll
      for (int j = 0; j < 8; j++) {
        float v = acc[i][j] + bv[j];
        acc[i][j] = v > 0.f ? v : av[j] * v;
      }
      float4 o0 = make_float4(acc[i][0], acc[i][1], acc[i][2], acc[i][3]);
      float4 o1 = make_float4(acc[i][4], acc[i][5], acc[i][6], acc[i][7]);
      *(float4*)&IO[(size_t)gr * D + tx * 8] = o0;
      *(float4*)&IO[(size_t)gr * D + tx * 8 + 4] = o1;
    }
  }
}

// ---------------- degree / CSR build ----------------

__global__ __launch_bounds__(256) void init_k(float* __restrict__ degw,
                                              int* __restrict__ cnt, int n) {
  int i = blockIdx.x * 256 + threadIdx.x;
  if (i < n) { degw[i] = 1.0f; cnt[i] = 0; }
}

__global__ __launch_bounds__(256) void count_k(const int* __restrict__ dst,
                                               const float* __restrict__ ew,
                                               float* __restrict__ degw,
                                               int* __restrict__ cnt, int E) {
  int e = blockIdx.x * 256 + threadIdx.x;
  if (e < E) {
    int d = dst[e];
    atomicAdd(&degw[d], ew[e]);
    atomicAdd(&cnt[d], 1);
  }
}

__global__ __launch_bounds__(256) void dinv_k(const float* __restrict__ degw,
                                              float* __restrict__ dinv, int n) {
  int i = blockIdx.x * 256 + threadIdx.x;
  if (i < n) dinv[i] = rsqrtf(degw[i]);  // degw >= 1 always (self loop)
}

// ---- hierarchical scan: partial sums -> scan partials -> per-block scan ----

__global__ __launch_bounds__(256) void scan_partial_k(const int* __restrict__ cnt,
                                                      int* __restrict__ partial,
                                                      int n) {
  __shared__ int sm[256];
  const int t = threadIdx.x;
  const int i = blockIdx.x * 256 + t;
  sm[t] = (i < n) ? cnt[i] : 0;
  __syncthreads();
  for (int off = 128; off > 0; off >>= 1) {
    if (t < off) sm[t] += sm[t + off];
    __syncthreads();
  }
  if (t == 0) partial[blockIdx.x] = sm[0];
}

__global__ __launch_bounds__(256) void scan_top_k(const int* __restrict__ partial,
                                                  int* __restrict__ poffs, int nb) {
  __shared__ int sm[256];
  const int t = threadIdx.x;
  int v = (t < nb) ? partial[t] : 0;
  sm[t] = v;
  __syncthreads();
  for (int off = 1; off < 256; off <<= 1) {
    int u = (t >= off) ? sm[t - off] : 0;
    __syncthreads();
    sm[t] += u;
    __syncthreads();
  }
  if (t < nb) poffs[t] = sm[t] - v;  // exclusive
}

__global__ __launch_bounds__(256) void scan_write_k(const int* __restrict__ cnt,
                                                    const int* __restrict__ poffs,
                                                    int* __restrict__ offs,
                                                    int* __restrict__ cursor, int n) {
  __shared__ int sm[256];
  const int t = threadIdx.x;
  const int i = blockIdx.x * 256 + t;
  int v = (i < n) ? cnt[i] : 0;
  sm[t] = v;
  __syncthreads();
  for (int off = 1; off < 256; off <<= 1) {
    int u = (t >= off) ? sm[t - off] : 0;
    __syncthreads();
    sm[t] += u;
    __syncthreads();
  }
  if (i < n) {
    int o = poffs[blockIdx.x] + sm[t] - v;  // exclusive prefix
    offs[i] = o;
    cursor[i] = o;
  }
}

// fill CSR entries: ee[pos] = (src, norm_bits)
__global__ __launch_bounds__(256) void fill_k(const int* __restrict__ src,
                                              const int* __restrict__ dst,
                                              const float* __restrict__ ew,
                                              const float* __restrict__ dinv,
                                              int* __restrict__ cursor,
                                              int2* __restrict__ ee, int E) {
  int e = blockIdx.x * 256 + threadIdx.x;
  if (e < E) {
    int s = src[e], d = dst[e];
    float w = ew[e] * dinv[s] * dinv[d];
    int pos = atomicAdd(&cursor[d], 1);
    ee[pos] = make_int2(s, __float_as_int(w));
  }
}

// ---------------- aggregation: 32 lanes per node, float4 per lane ----------------
// out[i] = sum_e norm_e * H[src_e] + dinv[i]^2 * H[i]  (+ bias, prelu if EPI)
template <int EPI>
__global__ __launch_bounds__(256) void gather_k(
    const float* __restrict__ H, const int* __restrict__ offs,
    const int* __restrict__ cnt, const int2* __restrict__ ee,
    const float* __restrict__ dinv, const float* __restrict__ bias,
    const float* __restrict__ pa, float* __restrict__ out, int n) {
  int g = blockIdx.x * 256 + threadIdx.x;
  int wid = g >> 5;   // node (2 nodes per wave)
  int lane = g & 31;
  if (wid >= n) return;
  const int st = offs[wid];
  const int len = cnt[wid];
  const int c = lane * 4;
  float ax = 0.f, ay = 0.f, az = 0.f, aw = 0.f;
  int j = 0;
  for (; j + 2 <= len; j += 2) {
    int2 p0 = ee[st + j];
    int2 p1 = ee[st + j + 1];
    float w0 = __int_as_float(p0.y);
    float w1 = __int_as_float(p1.y);
    float4 v0 = *(const float4*)&H[(size_t)p0.x * D + c];
    float4 v1 = *(const float4*)&H[(size_t)p1.x * D + c];
    ax += w0 * v0.x + w1 * v1.x;
    ay += w0 * v0.y + w1 * v1.y;
    az += w0 * v0.z + w1 * v1.z;
    aw += w0 * v0.w + w1 * v1.w;
  }
  if (j < len) {
    int2 p = ee[st + j];
    float w = __int_as_float(p.y);
    float4 v = *(const float4*)&H[(size_t)p.x * D + c];
    ax += w * v.x;
    ay += w * v.y;
    az += w * v.z;
    aw += w * v.w;
  }
  float dv = dinv[wid];
  float d2 = dv * dv;
  float4 h = *(const float4*)&H[(size_t)wid * D + c];
  ax += d2 * h.x;
  ay += d2 * h.y;
  az += d2 * h.z;
  aw += d2 * h.w;
  if (EPI) {
    ax += bias[c];
    ay += bias[c + 1];
    az += bias[c + 2];
    aw += bias[c + 3];
    ax = ax > 0.f ? ax : pa[c] * ax;
    ay = ay > 0.f ? ay : pa[c + 1] * ay;
    az = az > 0.f ? az : pa[c + 2] * az;
    aw = aw > 0.f ? aw : pa[c + 3] * aw;
  }
  *(float4*)&out[(size_t)wid * D + c] = make_float4(ax, ay, az, aw);
}

// ---------------- launch ----------------

extern "C" void kernel_launch(void* const* d_in, const int* in_sizes, int n_in,
                              void* d_out, int out_size, void* d_ws, size_t ws_size,
                              hipStream_t stream) {
  const float* x = (const float*)d_in[0];
  const int* ei = (const int*)d_in[1];       // [4][2][NE] int32
  const float* ew = (const float*)d_in[2];   // [4][NE]
  const float* W0 = (const float*)d_in[3];
  const float* b0 = (const float*)d_in[4];
  const float* W1 = (const float*)d_in[5];
  const float* b1 = (const float*)d_in[6];
  const float* pa = (const float*)d_in[7];
  float* out = (float*)d_out;                // [4][NN][D]

  float* H0 = (float*)d_ws;                  // 6.4M floats
  float* Z = H0 + (size_t)NN * D;            // 6.4M floats
  float* degw = Z + (size_t)NN * D;          // 50k
  float* dinv = degw + NN;                   // 50k
  int* cnt = (int*)(dinv + NN);              // 50k
  int* offs = cnt + NN;                      // 50k
  int* cursor = offs + NN;                   // 50k
  int* partial = cursor + NN;                // 256
  int* poffs = partial + 256;                // 256
  int2* ee = (int2*)(poffs + 256);           // 800k int2

  const int gGemm = (NN + 63) / 64;          // 782
  const int gNode = (NN + 255) / 256;        // 196
  const int gEdge = (NE + 255) / 256;        // 3125
  const int gGather = (NN * 32 + 255) / 256; // 6250

  // H0 = x @ W0 (shared across all scales)
  gemm_plain<<<gGemm, 256, 0, stream>>>(x, W0, H0, NN);

  for (int t = 0; t < 4; t++) {
    const int* src = ei + (size_t)t * 2 * NE;
    const int* dst = src + NE;
    const float* ewt = ew + (size_t)t * NE;
    float* outT = out + (size_t)t * NN * D;

    init_k<<<gNode, 256, 0, stream>>>(degw, cnt, NN);
    count_k<<<gEdge, 256, 0, stream>>>(dst, ewt, degw, cnt, NE);
    dinv_k<<<gNode, 256, 0, stream>>>(degw, dinv, NN);
    scan_partial_k<<<SCAN_BLOCKS, 256, 0, stream>>>(cnt, partial, NN);
    scan_top_k<<<1, 256, 0, stream>>>(partial, poffs, SCAN_BLOCKS);
    scan_write_k<<<SCAN_BLOCKS, 256, 0, stream>>>(cnt, poffs, offs, cursor, NN);
    fill_k<<<gEdge, 256, 0, stream>>>(src, dst, ewt, dinv, cursor, ee, NE);

    // layer 1: Z = prelu(Agg(H0) + b0)
    gather_k<1><<<gGather, 256, 0, stream>>>(H0, offs, cnt, ee, dinv, b0, pa, Z, NN);
    // layer 2: outT = Agg(Z); then outT = prelu(outT @ W1 + b1) in place
    gather_k<0><<<gGather, 256, 0, stream>>>(Z, offs, cnt, ee, dinv, nullptr, nullptr, outT, NN);
    gemm_epi<<<gGemm, 256, 0, stream>>>(outT, W1, b1, pa, NN);
  }
}

// Round 3
// 1126.038 us; speedup vs baseline: 1.8097x; 1.2071x over previous
//
#include <hip/hip_runtime.h>

#define NN 50000
#define NE 800000
#define D 128
#define SCAN_BLOCKS 196  // ceil(50000/256)
#define EW_SCALE 262144.0f      // 2^18 fixed-point for packed degree
#define EW_INV (1.0f / 262144.0f)

typedef unsigned long long ull;

// ---------------- GEMM: O[M x D] = X[M x D] @ W[D x D] ----------------
// 64-row tile, 256 threads, per-thread 4 rows x 8 cols.
// xs padded to stride 130 (conflict-free a-reads); W staged in 32-row k-chunks.

__global__ __launch_bounds__(256) void gemm_plain(
    const float* __restrict__ X, const float* __restrict__ W,
    float* __restrict__ O, int M) {
  __shared__ float xs[64 * 130];
  __shared__ float ws[32 * 128];
  const int tid = threadIdx.x;
  const int r0 = blockIdx.x * 64;
  for (int i = tid; i < 64 * 64; i += 256) {
    int row = i >> 6, kh = i & 63;
    float2 v = make_float2(0.f, 0.f);
    int gr = r0 + row;
    if (gr < M) v = *(const float2*)&X[(size_t)gr * D + kh * 2];
    *(float2*)&xs[row * 130 + kh * 2] = v;
  }
  const int tx = tid & 15, ty = tid >> 4;
  float acc[4][8];
#pragma unroll
  for (int i = 0; i < 4; i++)
#pragma unroll
    for (int j = 0; j < 8; j++) acc[i][j] = 0.f;

  for (int kc = 0; kc < 4; kc++) {
    __syncthreads();
    for (int i = tid; i < 32 * 32; i += 256) {
      ((float4*)ws)[i] = ((const float4*)(W + kc * 32 * D))[i];
    }
    __syncthreads();
#pragma unroll 4
    for (int k2 = 0; k2 < 32; k2++) {
      const int k = kc * 32 + k2;
      float a[4];
#pragma unroll
      for (int j = 0; j < 4; j++) a[j] = xs[(ty * 4 + j) * 130 + k];
      float4 b0 = *(const float4*)&ws[k2 * 128 + tx * 8];
      float4 b1 = *(const float4*)&ws[k2 * 128 + tx * 8 + 4];
      float b[8] = {b0.x, b0.y, b0.z, b0.w, b1.x, b1.y, b1.z, b1.w};
#pragma unroll
      for (int i = 0; i < 4; i++)
#pragma unroll
        for (int j = 0; j < 8; j++) acc[i][j] += a[i] * b[j];
    }
  }
#pragma unroll
  for (int i = 0; i < 4; i++) {
    int gr = r0 + ty * 4 + i;
    if (gr < M) {
      float4 o0 = make_float4(acc[i][0], acc[i][1], acc[i][2], acc[i][3]);
      float4 o1 = make_float4(acc[i][4], acc[i][5], acc[i][6], acc[i][7]);
      *(float4*)&O[(size_t)gr * D + tx * 8] = o0;
      *(float4*)&O[(size_t)gr * D + tx * 8 + 4] = o1;
    }
  }
}

// In-place: IO = prelu(IO @ W + bias). Each block reads/writes only its own rows.
__global__ __launch_bounds__(256) void gemm_epi(
    float* __restrict__ IO, const float* __restrict__ W,
    const float* __restrict__ bias, const float* __restrict__ pa, int M) {
  __shared__ float xs[64 * 130];
  __shared__ float ws[32 * 128];
  const int tid = threadIdx.x;
  const int r0 = blockIdx.x * 64;
  for (int i = tid; i < 64 * 64; i += 256) {
    int row = i >> 6, kh = i & 63;
    float2 v = make_float2(0.f, 0.f);
    int gr = r0 + row;
    if (gr < M) v = *(const float2*)&IO[(size_t)gr * D + kh * 2];
    *(float2*)&xs[row * 130 + kh * 2] = v;
  }
  const int tx = tid & 15, ty = tid >> 4;
  float bv[8], av[8];
#pragma unroll
  for (int j = 0; j < 8; j++) {
    bv[j] = bias[tx * 8 + j];
    av[j] = pa[tx * 8 + j];
  }
  float acc[4][8];
#pragma unroll
  for (int i = 0; i < 4; i++)
#pragma unroll
    for (int j = 0; j < 8; j++) acc[i][j] = 0.f;

  for (int kc = 0; kc < 4; kc++) {
    __syncthreads();
    for (int i = tid; i < 32 * 32; i += 256) {
      ((float4*)ws)[i] = ((const float4*)(W + kc * 32 * D))[i];
    }
    __syncthreads();
#pragma unroll 4
    for (int k2 = 0; k2 < 32; k2++) {
      const int k = kc * 32 + k2;
      float a[4];
#pragma unroll
      for (int j = 0; j < 4; j++) a[j] = xs[(ty * 4 + j) * 130 + k];
      float4 b0 = *(const float4*)&ws[k2 * 128 + tx * 8];
      float4 b1 = *(const float4*)&ws[k2 * 128 + tx * 8 + 4];
      float b[8] = {b0.x, b0.y, b0.z, b0.w, b1.x, b1.y, b1.z, b1.w};
#pragma unroll
      for (int i = 0; i < 4; i++)
#pragma unroll
        for (int j = 0; j < 8; j++) acc[i][j] += a[i] * b[j];
    }
  }
#pragma unroll
  for (int i = 0; i < 4; i++) {
    int gr = r0 + ty * 4 + i;
    if (gr < M) {
#pragma unroll
      for (int j = 0; j < 8; j++) {
        float v = acc[i][j] + bv[j];
        acc[i][j] = v > 0.f ? v : av[j] * v;
      }
      float4 o0 = make_float4(acc[i][0], acc[i][1], acc[i][2], acc[i][3]);
      float4 o1 = make_float4(acc[i][4], acc[i][5], acc[i][6], acc[i][7]);
      *(float4*)&IO[(size_t)gr * D + tx * 8] = o0;
      *(float4*)&IO[(size_t)gr * D + tx * 8 + 4] = o1;
    }
  }
}

// ---------------- degree / CSR build (single-atomic pipeline) ----------------

__global__ __launch_bounds__(256) void initp_k(ull* __restrict__ packed, int n) {
  int i = blockIdx.x * 256 + threadIdx.x;
  if (i < n) packed[i] = 0ULL;
}

// ONE atomic per edge: high word counts edges, low word accumulates fixed-point ew.
// Returned old high word = this edge's slot within its dst bucket.
__global__ __launch_bounds__(256) void countpos_k(const int* __restrict__ dst,
                                                  const float* __restrict__ ew,
                                                  ull* __restrict__ packed,
                                                  int* __restrict__ pos, int E) {
  int e = blockIdx.x * 256 + threadIdx.x;
  if (e < E) {
    int d = dst[e];
    ull add = (1ULL << 32) | (ull)__float2uint_rn(ew[e] * EW_SCALE);
    ull old = atomicAdd(&packed[d], add);
    pos[e] = (int)(old >> 32);
  }
}

__global__ __launch_bounds__(256) void unpack_k(const ull* __restrict__ packed,
                                                float* __restrict__ dinv,
                                                int* __restrict__ cnt, int n) {
  int i = blockIdx.x * 256 + threadIdx.x;
  if (i < n) {
    ull p = packed[i];
    cnt[i] = (int)(p >> 32);
    float deg = 1.0f + (float)(unsigned int)(p & 0xffffffffULL) * EW_INV;
    dinv[i] = rsqrtf(deg);  // deg >= 1 always (self loop)
  }
}

// ---- hierarchical scan: partial sums -> scan partials -> per-block scan ----

__global__ __launch_bounds__(256) void scan_partial_k(const int* __restrict__ cnt,
                                                      int* __restrict__ partial,
                                                      int n) {
  __shared__ int sm[256];
  const int t = threadIdx.x;
  const int i = blockIdx.x * 256 + t;
  sm[t] = (i < n) ? cnt[i] : 0;
  __syncthreads();
  for (int off = 128; off > 0; off >>= 1) {
    if (t < off) sm[t] += sm[t + off];
    __syncthreads();
  }
  if (t == 0) partial[blockIdx.x] = sm[0];
}

__global__ __launch_bounds__(256) void scan_top_k(const int* __restrict__ partial,
                                                  int* __restrict__ poffs, int nb) {
  __shared__ int sm[256];
  const int t = threadIdx.x;
  int v = (t < nb) ? partial[t] : 0;
  sm[t] = v;
  __syncthreads();
  for (int off = 1; off < 256; off <<= 1) {
    int u = (t >= off) ? sm[t - off] : 0;
    __syncthreads();
    sm[t] += u;
    __syncthreads();
  }
  if (t < nb) poffs[t] = sm[t] - v;  // exclusive
}

__global__ __launch_bounds__(256) void scan_write_k(const int* __restrict__ cnt,
                                                    const int* __restrict__ poffs,
                                                    int* __restrict__ offs, int n) {
  __shared__ int sm[256];
  const int t = threadIdx.x;
  const int i = blockIdx.x * 256 + t;
  int v = (i < n) ? cnt[i] : 0;
  sm[t] = v;
  __syncthreads();
  for (int off = 1; off < 256; off <<= 1) {
    int u = (t >= off) ? sm[t - off] : 0;
    __syncthreads();
    sm[t] += u;
    __syncthreads();
  }
  if (i < n) offs[i] = poffs[blockIdx.x] + sm[t] - v;  // exclusive prefix
}

// fill CSR entries (no atomics): ee[offs[d] + pos[e]] = (src, norm_bits)
__global__ __launch_bounds__(256) void fill_k(const int* __restrict__ src,
                                              const int* __restrict__ dst,
                                              const float* __restrict__ ew,
                                              const float* __restrict__ dinv,
                                              const int* __restrict__ offs,
                                              const int* __restrict__ pos,
                                              int2* __restrict__ ee, int E) {
  int e = blockIdx.x * 256 + threadIdx.x;
  if (e < E) {
    int s = src[e], d = dst[e];
    float w = ew[e] * dinv[s] * dinv[d];
    ee[offs[d] + pos[e]] = make_int2(s, __float_as_int(w));
  }
}

// ---------------- aggregation: 32 lanes per node, float4 per lane ----------------
// out[i] = sum_e norm_e * H[src_e] + dinv[i]^2 * H[i]  (+ bias, prelu if EPI)
template <int EPI>
__global__ __launch_bounds__(256) void gather_k(
    const float* __restrict__ H, const int* __restrict__ offs,
    const int* __restrict__ cnt, const int2* __restrict__ ee,
    const float* __restrict__ dinv, const float* __restrict__ bias,
    const float* __restrict__ pa, float* __restrict__ out, int n) {
  int g = blockIdx.x * 256 + threadIdx.x;
  int wid = g >> 5;   // node (2 nodes per wave)
  int lane = g & 31;
  if (wid >= n) return;
  const int st = offs[wid];
  const int len = cnt[wid];
  const int c = lane * 4;
  float ax = 0.f, ay = 0.f, az = 0.f, aw = 0.f;
  int j = 0;
  for (; j + 2 <= len; j += 2) {
    int2 p0 = ee[st + j];
    int2 p1 = ee[st + j + 1];
    float w0 = __int_as_float(p0.y);
    float w1 = __int_as_float(p1.y);
    float4 v0 = *(const float4*)&H[(size_t)p0.x * D + c];
    float4 v1 = *(const float4*)&H[(size_t)p1.x * D + c];
    ax += w0 * v0.x + w1 * v1.x;
    ay += w0 * v0.y + w1 * v1.y;
    az += w0 * v0.z + w1 * v1.z;
    aw += w0 * v0.w + w1 * v1.w;
  }
  if (j < len) {
    int2 p = ee[st + j];
    float w = __int_as_float(p.y);
    float4 v = *(const float4*)&H[(size_t)p.x * D + c];
    ax += w * v.x;
    ay += w * v.y;
    az += w * v.z;
    aw += w * v.w;
  }
  float dv = dinv[wid];
  float d2 = dv * dv;
  float4 h = *(const float4*)&H[(size_t)wid * D + c];
  ax += d2 * h.x;
  ay += d2 * h.y;
  az += d2 * h.z;
  aw += d2 * h.w;
  if (EPI) {
    ax += bias[c];
    ay += bias[c + 1];
    az += bias[c + 2];
    aw += bias[c + 3];
    ax = ax > 0.f ? ax : pa[c] * ax;
    ay = ay > 0.f ? ay : pa[c + 1] * ay;
    az = az > 0.f ? az : pa[c + 2] * az;
    aw = aw > 0.f ? aw : pa[c + 3] * aw;
  }
  *(float4*)&out[(size_t)wid * D + c] = make_float4(ax, ay, az, aw);
}

// ---------------- launch ----------------

extern "C" void kernel_launch(void* const* d_in, const int* in_sizes, int n_in,
                              void* d_out, int out_size, void* d_ws, size_t ws_size,
                              hipStream_t stream) {
  const float* x = (const float*)d_in[0];
  const int* ei = (const int*)d_in[1];       // [4][2][NE] int32
  const float* ew = (const float*)d_in[2];   // [4][NE]
  const float* W0 = (const float*)d_in[3];
  const float* b0 = (const float*)d_in[4];
  const float* W1 = (const float*)d_in[5];
  const float* b1 = (const float*)d_in[6];
  const float* pa = (const float*)d_in[7];
  float* out = (float*)d_out;                // [4][NN][D]

  float* H0 = (float*)d_ws;                  // 6.4M floats
  float* Z = H0 + (size_t)NN * D;            // 6.4M floats
  float* dinv = Z + (size_t)NN * D;          // 50k
  int* cnt = (int*)(dinv + NN);              // 50k
  int* offs = cnt + NN;                      // 50k
  int* partial = offs + NN;                  // 256
  int* poffs = partial + 256;                // 256
  ull* packed = (ull*)(poffs + 256);         // 50k ull (8B-aligned: prefix is even # of 4B words)
  int2* ee = (int2*)(packed + NN);           // 800k int2
  int* pos = (int*)Z;                        // aliased: pos dead before gather1 writes Z

  const int gGemm = (NN + 63) / 64;          // 782
  const int gNode = (NN + 255) / 256;        // 196
  const int gEdge = (NE + 255) / 256;        // 3125
  const int gGather = (NN * 32 + 255) / 256; // 6250

  // H0 = x @ W0 (shared across all scales)
  gemm_plain<<<gGemm, 256, 0, stream>>>(x, W0, H0, NN);

  for (int t = 0; t < 4; t++) {
    const int* src = ei + (size_t)t * 2 * NE;
    const int* dst = src + NE;
    const float* ewt = ew + (size_t)t * NE;
    float* outT = out + (size_t)t * NN * D;

    initp_k<<<gNode, 256, 0, stream>>>(packed, NN);
    countpos_k<<<gEdge, 256, 0, stream>>>(dst, ewt, packed, pos, NE);
    unpack_k<<<gNode, 256, 0, stream>>>(packed, dinv, cnt, NN);
    scan_partial_k<<<SCAN_BLOCKS, 256, 0, stream>>>(cnt, partial, NN);
    scan_top_k<<<1, 256, 0, stream>>>(partial, poffs, SCAN_BLOCKS);
    scan_write_k<<<SCAN_BLOCKS, 256, 0, stream>>>(cnt, poffs, offs, NN);
    fill_k<<<gEdge, 256, 0, stream>>>(src, dst, ewt, dinv, offs, pos, ee, NE);

    // layer 1: Z = prelu(Agg(H0) + b0)   (overwrites pos — pos is dead by now)
    gather_k<1><<<gGather, 256, 0, stream>>>(H0, offs, cnt, ee, dinv, b0, pa, Z, NN);
    // layer 2: outT = Agg(Z); then outT = prelu(outT @ W1 + b1) in place
    gather_k<0><<<gGather, 256, 0, stream>>>(Z, offs, cnt, ee, dinv, nullptr, nullptr, outT, NN);
    gemm_epi<<<gGemm, 256, 0, stream>>>(outT, W1, b1, pa, NN);
  }
}

// Round 4
// 922.831 us; speedup vs baseline: 2.2083x; 1.2202x over previous
//
#include <hip/hip_runtime.h>

#define NN 50000
#define NE 800000
#define D 128
#define SCAN_BLOCKS 196  // ceil(50000/256)
#define EW_SCALE 262144.0f      // 2^18 fixed-point for packed degree
#define EW_INV (1.0f / 262144.0f)

typedef unsigned long long ull;

__device__ __forceinline__ unsigned short f2bf(float f) {
  unsigned int u = __float_as_uint(f);
  u += 0x7fffu + ((u >> 16) & 1u);  // RNE
  return (unsigned short)(u >> 16);
}
__device__ __forceinline__ float bf2f(unsigned short h) {
  return __uint_as_float((unsigned int)h << 16);
}

// ---------------- GEMM: H0h[M x D] (bf16) = X[M x D] @ W[D x D] ----------------

__global__ __launch_bounds__(256) void gemm_plain_bf16out(
    const float* __restrict__ X, const float* __restrict__ W,
    unsigned short* __restrict__ O, int M) {
  __shared__ float xs[64 * 130];
  __shared__ float ws[32 * 128];
  const int tid = threadIdx.x;
  const int r0 = blockIdx.x * 64;
  for (int i = tid; i < 64 * 64; i += 256) {
    int row = i >> 6, kh = i & 63;
    float2 v = make_float2(0.f, 0.f);
    int gr = r0 + row;
    if (gr < M) v = *(const float2*)&X[(size_t)gr * D + kh * 2];
    *(float2*)&xs[row * 130 + kh * 2] = v;
  }
  const int tx = tid & 15, ty = tid >> 4;
  float acc[4][8];
#pragma unroll
  for (int i = 0; i < 4; i++)
#pragma unroll
    for (int j = 0; j < 8; j++) acc[i][j] = 0.f;

  for (int kc = 0; kc < 4; kc++) {
    __syncthreads();
    for (int i = tid; i < 32 * 32; i += 256) {
      ((float4*)ws)[i] = ((const float4*)(W + kc * 32 * D))[i];
    }
    __syncthreads();
#pragma unroll 4
    for (int k2 = 0; k2 < 32; k2++) {
      const int k = kc * 32 + k2;
      float a[4];
#pragma unroll
      for (int j = 0; j < 4; j++) a[j] = xs[(ty * 4 + j) * 130 + k];
      float4 b0 = *(const float4*)&ws[k2 * 128 + tx * 8];
      float4 b1 = *(const float4*)&ws[k2 * 128 + tx * 8 + 4];
      float b[8] = {b0.x, b0.y, b0.z, b0.w, b1.x, b1.y, b1.z, b1.w};
#pragma unroll
      for (int i = 0; i < 4; i++)
#pragma unroll
        for (int j = 0; j < 8; j++) acc[i][j] += a[i] * b[j];
    }
  }
#pragma unroll
  for (int i = 0; i < 4; i++) {
    int gr = r0 + ty * 4 + i;
    if (gr < M) {
      ushort4 o0, o1;
      o0.x = f2bf(acc[i][0]); o0.y = f2bf(acc[i][1]);
      o0.z = f2bf(acc[i][2]); o0.w = f2bf(acc[i][3]);
      o1.x = f2bf(acc[i][4]); o1.y = f2bf(acc[i][5]);
      o1.z = f2bf(acc[i][6]); o1.w = f2bf(acc[i][7]);
      *(ushort4*)&O[(size_t)gr * D + tx * 8] = o0;
      *(ushort4*)&O[(size_t)gr * D + tx * 8 + 4] = o1;
    }
  }
}

// In-place: IO = prelu(IO @ W + bias), fp32. Each block touches only its own rows.
__global__ __launch_bounds__(256) void gemm_epi(
    float* __restrict__ IO, const float* __restrict__ W,
    const float* __restrict__ bias, const float* __restrict__ pa, int M) {
  __shared__ float xs[64 * 130];
  __shared__ float ws[32 * 128];
  const int tid = threadIdx.x;
  const int r0 = blockIdx.x * 64;
  for (int i = tid; i < 64 * 64; i += 256) {
    int row = i >> 6, kh = i & 63;
    float2 v = make_float2(0.f, 0.f);
    int gr = r0 + row;
    if (gr < M) v = *(const float2*)&IO[(size_t)gr * D + kh * 2];
    *(float2*)&xs[row * 130 + kh * 2] = v;
  }
  const int tx = tid & 15, ty = tid >> 4;
  float bv[8], av[8];
#pragma unroll
  for (int j = 0; j < 8; j++) {
    bv[j] = bias[tx * 8 + j];
    av[j] = pa[tx * 8 + j];
  }
  float acc[4][8];
#pragma unroll
  for (int i = 0; i < 4; i++)
#pragma unroll
    for (int j = 0; j < 8; j++) acc[i][j] = 0.f;

  for (int kc = 0; kc < 4; kc++) {
    __syncthreads();
    for (int i = tid; i < 32 * 32; i += 256) {
      ((float4*)ws)[i] = ((const float4*)(W + kc * 32 * D))[i];
    }
    __syncthreads();
#pragma unroll 4
    for (int k2 = 0; k2 < 32; k2++) {
      const int k = kc * 32 + k2;
      float a[4];
#pragma unroll
      for (int j = 0; j < 4; j++) a[j] = xs[(ty * 4 + j) * 130 + k];
      float4 b0 = *(const float4*)&ws[k2 * 128 + tx * 8];
      float4 b1 = *(const float4*)&ws[k2 * 128 + tx * 8 + 4];
      float b[8] = {b0.x, b0.y, b0.z, b0.w, b1.x, b1.y, b1.z, b1.w};
#pragma unroll
      for (int i = 0; i < 4; i++)
#pragma unroll
        for (int j = 0; j < 8; j++) acc[i][j] += a[i] * b[j];
    }
  }
#pragma unroll
  for (int i = 0; i < 4; i++) {
    int gr = r0 + ty * 4 + i;
    if (gr < M) {
#pragma unroll
      for (int j = 0; j < 8; j++) {
        float v = acc[i][j] + bv[j];
        acc[i][j] = v > 0.f ? v : av[j] * v;
      }
      float4 o0 = make_float4(acc[i][0], acc[i][1], acc[i][2], acc[i][3]);
      float4 o1 = make_float4(acc[i][4], acc[i][5], acc[i][6], acc[i][7]);
      *(float4*)&IO[(size_t)gr * D + tx * 8] = o0;
      *(float4*)&IO[(size_t)gr * D + tx * 8 + 4] = o1;
    }
  }
}

// ---------------- degree / CSR build (single-atomic pipeline) ----------------

__global__ __launch_bounds__(256) void initp_k(ull* __restrict__ packed, int n) {
  int i = blockIdx.x * 256 + threadIdx.x;
  if (i < n) packed[i] = 0ULL;
}

__global__ __launch_bounds__(256) void countpos_k(const int* __restrict__ dst,
                                                  const float* __restrict__ ew,
                                                  ull* __restrict__ packed,
                                                  int* __restrict__ pos, int E) {
  int e = blockIdx.x * 256 + threadIdx.x;
  if (e < E) {
    int d = dst[e];
    ull add = (1ULL << 32) | (ull)__float2uint_rn(ew[e] * EW_SCALE);
    ull old = atomicAdd(&packed[d], add);
    pos[e] = (int)(old >> 32);
  }
}

__global__ __launch_bounds__(256) void unpack_k(const ull* __restrict__ packed,
                                                float* __restrict__ dinv,
                                                int* __restrict__ cnt, int n) {
  int i = blockIdx.x * 256 + threadIdx.x;
  if (i < n) {
    ull p = packed[i];
    cnt[i] = (int)(p >> 32);
    float deg = 1.0f + (float)(unsigned int)(p & 0xffffffffULL) * EW_INV;
    dinv[i] = rsqrtf(deg);
  }
}

// ---- hierarchical scan ----

__global__ __launch_bounds__(256) void scan_partial_k(const int* __restrict__ cnt,
                                                      int* __restrict__ partial,
                                                      int n) {
  __shared__ int sm[256];
  const int t = threadIdx.x;
  const int i = blockIdx.x * 256 + t;
  sm[t] = (i < n) ? cnt[i] : 0;
  __syncthreads();
  for (int off = 128; off > 0; off >>= 1) {
    if (t < off) sm[t] += sm[t + off];
    __syncthreads();
  }
  if (t == 0) partial[blockIdx.x] = sm[0];
}

__global__ __launch_bounds__(256) void scan_top_k(const int* __restrict__ partial,
                                                  int* __restrict__ poffs, int nb) {
  __shared__ int sm[256];
  const int t = threadIdx.x;
  int v = (t < nb) ? partial[t] : 0;
  sm[t] = v;
  __syncthreads();
  for (int off = 1; off < 256; off <<= 1) {
    int u = (t >= off) ? sm[t - off] : 0;
    __syncthreads();
    sm[t] += u;
    __syncthreads();
  }
  if (t < nb) poffs[t] = sm[t] - v;
}

__global__ __launch_bounds__(256) void scan_write_k(const int* __restrict__ cnt,
                                                    const int* __restrict__ poffs,
                                                    int* __restrict__ offs, int n) {
  __shared__ int sm[256];
  const int t = threadIdx.x;
  const int i = blockIdx.x * 256 + t;
  int v = (i < n) ? cnt[i] : 0;
  sm[t] = v;
  __syncthreads();
  for (int off = 1; off < 256; off <<= 1) {
    int u = (t >= off) ? sm[t - off] : 0;
    __syncthreads();
    sm[t] += u;
    __syncthreads();
  }
  if (i < n) offs[i] = poffs[blockIdx.x] + sm[t] - v;
}

// fill CSR entries (no atomics): ee[offs[d] + pos[e]] = (src, norm_bits)
__global__ __launch_bounds__(256) void fill_k(const int* __restrict__ src,
                                              const int* __restrict__ dst,
                                              const float* __restrict__ ew,
                                              const float* __restrict__ dinv,
                                              const int* __restrict__ offs,
                                              const int* __restrict__ pos,
                                              int2* __restrict__ ee, int E) {
  int e = blockIdx.x * 256 + threadIdx.x;
  if (e < E) {
    int s = src[e], d = dst[e];
    float w = ew[e] * dinv[s] * dinv[d];
    ee[offs[d] + pos[e]] = make_int2(s, __float_as_int(w));
  }
}

// ---------------- aggregation: 32 lanes/node, bf16 rows (8B/lane), fp32 acc ----
// OUT_BF16=1: out row is bf16 (inter-layer Z).  OUT_BF16=0: out row is fp32.
template <int EPI, int OUT_BF16>
__global__ __launch_bounds__(256) void gather_k(
    const unsigned short* __restrict__ H, const int* __restrict__ offs,
    const int* __restrict__ cnt, const int2* __restrict__ ee,
    const float* __restrict__ dinv, const float* __restrict__ bias,
    const float* __restrict__ pa, void* __restrict__ outv, int n) {
  int g = blockIdx.x * 256 + threadIdx.x;
  int wid = g >> 5;   // node (2 nodes per wave)
  int lane = g & 31;
  if (wid >= n) return;
  const int st = offs[wid];
  const int len = cnt[wid];
  const int c = lane * 4;
  float ax = 0.f, ay = 0.f, az = 0.f, aw = 0.f;
  int j = 0;
  for (; j + 4 <= len; j += 4) {
    int2 p0 = ee[st + j];
    int2 p1 = ee[st + j + 1];
    int2 p2 = ee[st + j + 2];
    int2 p3 = ee[st + j + 3];
    ushort4 v0 = *(const ushort4*)&H[(size_t)p0.x * D + c];
    ushort4 v1 = *(const ushort4*)&H[(size_t)p1.x * D + c];
    ushort4 v2 = *(const ushort4*)&H[(size_t)p2.x * D + c];
    ushort4 v3 = *(const ushort4*)&H[(size_t)p3.x * D + c];
    float w0 = __int_as_float(p0.y), w1 = __int_as_float(p1.y);
    float w2 = __int_as_float(p2.y), w3 = __int_as_float(p3.y);
    ax += w0 * bf2f(v0.x) + w1 * bf2f(v1.x) + w2 * bf2f(v2.x) + w3 * bf2f(v3.x);
    ay += w0 * bf2f(v0.y) + w1 * bf2f(v1.y) + w2 * bf2f(v2.y) + w3 * bf2f(v3.y);
    az += w0 * bf2f(v0.z) + w1 * bf2f(v1.z) + w2 * bf2f(v2.z) + w3 * bf2f(v3.z);
    aw += w0 * bf2f(v0.w) + w1 * bf2f(v1.w) + w2 * bf2f(v2.w) + w3 * bf2f(v3.w);
  }
  for (; j < len; j++) {
    int2 p = ee[st + j];
    float w = __int_as_float(p.y);
    ushort4 v = *(const ushort4*)&H[(size_t)p.x * D + c];
    ax += w * bf2f(v.x);
    ay += w * bf2f(v.y);
    az += w * bf2f(v.z);
    aw += w * bf2f(v.w);
  }
  float dv = dinv[wid];
  float d2 = dv * dv;
  ushort4 h = *(const ushort4*)&H[(size_t)wid * D + c];
  ax += d2 * bf2f(h.x);
  ay += d2 * bf2f(h.y);
  az += d2 * bf2f(h.z);
  aw += d2 * bf2f(h.w);
  if (EPI) {
    ax += bias[c];
    ay += bias[c + 1];
    az += bias[c + 2];
    aw += bias[c + 3];
    ax = ax > 0.f ? ax : pa[c] * ax;
    ay = ay > 0.f ? ay : pa[c + 1] * ay;
    az = az > 0.f ? az : pa[c + 2] * az;
    aw = aw > 0.f ? aw : pa[c + 3] * aw;
  }
  if (OUT_BF16) {
    ushort4 o;
    o.x = f2bf(ax); o.y = f2bf(ay); o.z = f2bf(az); o.w = f2bf(aw);
    *(ushort4*)&((unsigned short*)outv)[(size_t)wid * D + c] = o;
  } else {
    *(float4*)&((float*)outv)[(size_t)wid * D + c] = make_float4(ax, ay, az, aw);
  }
}

// ---------------- launch ----------------

extern "C" void kernel_launch(void* const* d_in, const int* in_sizes, int n_in,
                              void* d_out, int out_size, void* d_ws, size_t ws_size,
                              hipStream_t stream) {
  const float* x = (const float*)d_in[0];
  const int* ei = (const int*)d_in[1];       // [4][2][NE] int32
  const float* ew = (const float*)d_in[2];   // [4][NE]
  const float* W0 = (const float*)d_in[3];
  const float* b0 = (const float*)d_in[4];
  const float* W1 = (const float*)d_in[5];
  const float* b1 = (const float*)d_in[6];
  const float* pa = (const float*)d_in[7];
  float* out = (float*)d_out;                // [4][NN][D] fp32

  unsigned short* H0h = (unsigned short*)d_ws;          // 6.4M bf16 (12.8 MB)
  unsigned short* Zh = H0h + (size_t)NN * D;            // 6.4M bf16 (12.8 MB)
  float* dinv = (float*)(Zh + (size_t)NN * D);          // 50k
  int* cnt = (int*)(dinv + NN);                         // 50k
  int* offs = cnt + NN;                                 // 50k
  int* partial = offs + NN;                             // 256
  int* poffs = partial + 256;                           // 256
  ull* packed = (ull*)(poffs + 256);                    // 50k ull (8B-aligned)
  int* pos = (int*)(packed + NN);                       // 800k int
  int2* ee = (int2*)(pos + NE);                         // 800k int2

  const int gGemm = (NN + 63) / 64;          // 782
  const int gNode = (NN + 255) / 256;        // 196
  const int gEdge = (NE + 255) / 256;        // 3125
  const int gGather = (NN * 32 + 255) / 256; // 6250

  // H0h = bf16(x @ W0) (shared across all scales)
  gemm_plain_bf16out<<<gGemm, 256, 0, stream>>>(x, W0, H0h, NN);

  for (int t = 0; t < 4; t++) {
    const int* src = ei + (size_t)t * 2 * NE;
    const int* dst = src + NE;
    const float* ewt = ew + (size_t)t * NE;
    float* outT = out + (size_t)t * NN * D;

    initp_k<<<gNode, 256, 0, stream>>>(packed, NN);
    countpos_k<<<gEdge, 256, 0, stream>>>(dst, ewt, packed, pos, NE);
    unpack_k<<<gNode, 256, 0, stream>>>(packed, dinv, cnt, NN);
    scan_partial_k<<<SCAN_BLOCKS, 256, 0, stream>>>(cnt, partial, NN);
    scan_top_k<<<1, 256, 0, stream>>>(partial, poffs, SCAN_BLOCKS);
    scan_write_k<<<SCAN_BLOCKS, 256, 0, stream>>>(cnt, poffs, offs, NN);
    fill_k<<<gEdge, 256, 0, stream>>>(src, dst, ewt, dinv, offs, pos, ee, NE);

    // layer 1: Zh = bf16(prelu(Agg(H0h) + b0))
    gather_k<1, 1><<<gGather, 256, 0, stream>>>(H0h, offs, cnt, ee, dinv, b0, pa, Zh, NN);
    // layer 2: outT = Agg(Zh) fp32; then outT = prelu(outT @ W1 + b1) in place
    gather_k<0, 0><<<gGather, 256, 0, stream>>>(Zh, offs, cnt, ee, dinv, nullptr, nullptr, outT, NN);
    gemm_epi<<<gGemm, 256, 0, stream>>>(outT, W1, b1, pa, NN);
  }
}

// Round 5
// 819.037 us; speedup vs baseline: 2.4881x; 1.1267x over previous
//
#include <hip/hip_runtime.h>

#define NN 50000
#define NE 800000
#define NS 4
#define NT (NS * NN)          // 200000
#define D 128
#define SB2 782               // ceil(NT/256)
#define EW_SCALE 262144.0f    // 2^18 fixed-point for packed degree
#define EW_INV (1.0f / 262144.0f)

typedef unsigned long long ull;

__device__ __forceinline__ unsigned short f2bf(float f) {
  unsigned int u = __float_as_uint(f);
  u += 0x7fffu + ((u >> 16) & 1u);  // RNE
  return (unsigned short)(u >> 16);
}
__device__ __forceinline__ float bf2f(unsigned short h) {
  return __uint_as_float((unsigned int)h << 16);
}

// ---------------- GEMM: H0h[M x D] (bf16) = X[M x D] @ W[D x D] ----------------

__global__ __launch_bounds__(256) void gemm_plain_bf16out(
    const float* __restrict__ X, const float* __restrict__ W,
    unsigned short* __restrict__ O, int M) {
  __shared__ float xs[64 * 130];
  __shared__ float ws[32 * 128];
  const int tid = threadIdx.x;
  const int r0 = blockIdx.x * 64;
  for (int i = tid; i < 64 * 64; i += 256) {
    int row = i >> 6, kh = i & 63;
    float2 v = make_float2(0.f, 0.f);
    int gr = r0 + row;
    if (gr < M) v = *(const float2*)&X[(size_t)gr * D + kh * 2];
    *(float2*)&xs[row * 130 + kh * 2] = v;
  }
  const int tx = tid & 15, ty = tid >> 4;
  float acc[4][8];
#pragma unroll
  for (int i = 0; i < 4; i++)
#pragma unroll
    for (int j = 0; j < 8; j++) acc[i][j] = 0.f;

  for (int kc = 0; kc < 4; kc++) {
    __syncthreads();
    for (int i = tid; i < 32 * 32; i += 256) {
      ((float4*)ws)[i] = ((const float4*)(W + kc * 32 * D))[i];
    }
    __syncthreads();
#pragma unroll 4
    for (int k2 = 0; k2 < 32; k2++) {
      const int k = kc * 32 + k2;
      float a[4];
#pragma unroll
      for (int j = 0; j < 4; j++) a[j] = xs[(ty * 4 + j) * 130 + k];
      float4 b0 = *(const float4*)&ws[k2 * 128 + tx * 8];
      float4 b1 = *(const float4*)&ws[k2 * 128 + tx * 8 + 4];
      float b[8] = {b0.x, b0.y, b0.z, b0.w, b1.x, b1.y, b1.z, b1.w};
#pragma unroll
      for (int i = 0; i < 4; i++)
#pragma unroll
        for (int j = 0; j < 8; j++) acc[i][j] += a[i] * b[j];
    }
  }
#pragma unroll
  for (int i = 0; i < 4; i++) {
    int gr = r0 + ty * 4 + i;
    if (gr < M) {
      ushort4 o0, o1;
      o0.x = f2bf(acc[i][0]); o0.y = f2bf(acc[i][1]);
      o0.z = f2bf(acc[i][2]); o0.w = f2bf(acc[i][3]);
      o1.x = f2bf(acc[i][4]); o1.y = f2bf(acc[i][5]);
      o1.z = f2bf(acc[i][6]); o1.w = f2bf(acc[i][7]);
      *(ushort4*)&O[(size_t)gr * D + tx * 8] = o0;
      *(ushort4*)&O[(size_t)gr * D + tx * 8 + 4] = o1;
    }
  }
}

// ---------------- CSR build, batched over all 4 scales ----------------

__global__ __launch_bounds__(256) void initp_k(ull* __restrict__ packed, int n) {
  int i = blockIdx.x * 256 + threadIdx.x;
  if (i < n) packed[i] = 0ULL;
}

// grid (3125, NS). ONE 64-bit atomic per edge; old high word = slot in dst bucket.
__global__ __launch_bounds__(256) void countpos_all_k(const int* __restrict__ ei,
                                                      const float* __restrict__ ewA,
                                                      ull* __restrict__ packedA,
                                                      int* __restrict__ posA) {
  const int t = blockIdx.y;
  const int e = blockIdx.x * 256 + threadIdx.x;
  if (e < NE) {
    const int* dst = ei + (size_t)t * 2 * NE + NE;
    int d = dst[e];
    float w = ewA[(size_t)t * NE + e];
    ull add = (1ULL << 32) | (ull)__float2uint_rn(w * EW_SCALE);
    ull old = atomicAdd(&packedA[t * NN + d], add);
    posA[(size_t)t * NE + e] = (int)(old >> 32);
  }
}

// unpack + per-block partial sum (fused). grid SB2 over NT.
__global__ __launch_bounds__(256) void unpack_scan_k(const ull* __restrict__ packedA,
                                                     float* __restrict__ dinvA,
                                                     int* __restrict__ cntA,
                                                     int* __restrict__ partial) {
  __shared__ int sm[256];
  const int tid = threadIdx.x;
  const int i = blockIdx.x * 256 + tid;
  int c = 0;
  if (i < NT) {
    ull p = packedA[i];
    c = (int)(p >> 32);
    cntA[i] = c;
    float deg = 1.0f + (float)(unsigned int)(p & 0xffffffffULL) * EW_INV;
    dinvA[i] = rsqrtf(deg);
  }
  sm[tid] = c;
  __syncthreads();
  for (int off = 128; off > 0; off >>= 1) {
    if (tid < off) sm[tid] += sm[tid + off];
    __syncthreads();
  }
  if (tid == 0) partial[blockIdx.x] = sm[0];
}

// single block: exclusive scan of SB2 partials (chunked serial + block scan)
__global__ __launch_bounds__(256) void scan_top_k(const int* __restrict__ partial,
                                                  int* __restrict__ poffs, int nb) {
  __shared__ int sm[256];
  const int t = threadIdx.x;
  const int chunk = (nb + 255) >> 8;
  const int lo = t * chunk;
  const int hi = min(lo + chunk, nb);
  int s = 0;
  for (int i = lo; i < hi; i++) s += partial[i];
  sm[t] = s;
  __syncthreads();
  for (int off = 1; off < 256; off <<= 1) {
    int u = (t >= off) ? sm[t - off] : 0;
    __syncthreads();
    sm[t] += u;
    __syncthreads();
  }
  int run = sm[t] - s;  // exclusive
  for (int i = lo; i < hi; i++) {
    poffs[i] = run;
    run += partial[i];
  }
}

__global__ __launch_bounds__(256) void scan_write_k(const int* __restrict__ cntA,
                                                    const int* __restrict__ poffs,
                                                    int* __restrict__ offsA) {
  __shared__ int sm[256];
  const int t = threadIdx.x;
  const int i = blockIdx.x * 256 + t;
  int v = (i < NT) ? cntA[i] : 0;
  sm[t] = v;
  __syncthreads();
  for (int off = 1; off < 256; off <<= 1) {
    int u = (t >= off) ? sm[t - off] : 0;
    __syncthreads();
    sm[t] += u;
    __syncthreads();
  }
  if (i < NT) offsA[i] = poffs[blockIdx.x] + sm[t] - v;
}

// grid (3125, NS): eeA[offsA[t*NN+d] + pos] = (src, norm_bits). No atomics.
// Global scan => scale t's segment is exactly [t*NE, (t+1)*NE).
__global__ __launch_bounds__(256) void fill_all_k(const int* __restrict__ ei,
                                                  const float* __restrict__ ewA,
                                                  const float* __restrict__ dinvA,
                                                  const int* __restrict__ offsA,
                                                  const int* __restrict__ posA,
                                                  int2* __restrict__ eeA) {
  const int t = blockIdx.y;
  const int e = blockIdx.x * 256 + threadIdx.x;
  if (e < NE) {
    const int* src = ei + (size_t)t * 2 * NE;
    const int* dst = src + NE;
    int s = src[e], d = dst[e];
    float w = ewA[(size_t)t * NE + e] * dinvA[t * NN + s] * dinvA[t * NN + d];
    eeA[offsA[t * NN + d] + posA[(size_t)t * NE + e]] = make_int2(s, __float_as_int(w));
  }
}

// ---------------- layer-1 gather, batched: grid (6250, NS) ----------------
// Zh_t = bf16(prelu(Agg(H0h) + b0)); 32 lanes/node, ushort4/lane, fp32 acc.
__global__ __launch_bounds__(256) void gather1_all_k(
    const unsigned short* __restrict__ H, const int* __restrict__ offsA,
    const int* __restrict__ cntA, const int2* __restrict__ eeA,
    const float* __restrict__ dinvA, const float* __restrict__ bias,
    const float* __restrict__ pa, unsigned short* __restrict__ ZhA) {
  const int t = blockIdx.y;
  int g = blockIdx.x * 256 + threadIdx.x;
  int wid = g >> 5;
  int lane = g & 31;
  if (wid >= NN) return;
  const int base = t * NN + wid;
  const int st = offsA[base];
  const int len = cntA[base];
  const int c = lane * 4;
  float ax = 0.f, ay = 0.f, az = 0.f, aw = 0.f;
  int j = 0;
  for (; j + 4 <= len; j += 4) {
    int2 p0 = eeA[st + j];
    int2 p1 = eeA[st + j + 1];
    int2 p2 = eeA[st + j + 2];
    int2 p3 = eeA[st + j + 3];
    ushort4 v0 = *(const ushort4*)&H[(size_t)p0.x * D + c];
    ushort4 v1 = *(const ushort4*)&H[(size_t)p1.x * D + c];
    ushort4 v2 = *(const ushort4*)&H[(size_t)p2.x * D + c];
    ushort4 v3 = *(const ushort4*)&H[(size_t)p3.x * D + c];
    float w0 = __int_as_float(p0.y), w1 = __int_as_float(p1.y);
    float w2 = __int_as_float(p2.y), w3 = __int_as_float(p3.y);
    ax += w0 * bf2f(v0.x) + w1 * bf2f(v1.x) + w2 * bf2f(v2.x) + w3 * bf2f(v3.x);
    ay += w0 * bf2f(v0.y) + w1 * bf2f(v1.y) + w2 * bf2f(v2.y) + w3 * bf2f(v3.y);
    az += w0 * bf2f(v0.z) + w1 * bf2f(v1.z) + w2 * bf2f(v2.z) + w3 * bf2f(v3.z);
    aw += w0 * bf2f(v0.w) + w1 * bf2f(v1.w) + w2 * bf2f(v2.w) + w3 * bf2f(v3.w);
  }
  for (; j < len; j++) {
    int2 p = eeA[st + j];
    float w = __int_as_float(p.y);
    ushort4 v = *(const ushort4*)&H[(size_t)p.x * D + c];
    ax += w * bf2f(v.x);
    ay += w * bf2f(v.y);
    az += w * bf2f(v.z);
    aw += w * bf2f(v.w);
  }
  float dv = dinvA[base];
  float d2 = dv * dv;
  ushort4 h = *(const ushort4*)&H[(size_t)wid * D + c];
  ax += d2 * bf2f(h.x) + bias[c];
  ay += d2 * bf2f(h.y) + bias[c + 1];
  az += d2 * bf2f(h.z) + bias[c + 2];
  aw += d2 * bf2f(h.w) + bias[c + 3];
  ax = ax > 0.f ? ax : pa[c] * ax;
  ay = ay > 0.f ? ay : pa[c + 1] * ay;
  az = az > 0.f ? az : pa[c + 2] * az;
  aw = aw > 0.f ? aw : pa[c + 3] * aw;
  ushort4 o;
  o.x = f2bf(ax); o.y = f2bf(ay); o.z = f2bf(az); o.w = f2bf(aw);
  *(ushort4*)&ZhA[(size_t)t * NN * D + (size_t)wid * D + c] = o;
}

// ---------------- layer-2 fused: Agg(Zh_t) -> LDS -> @W1 + b1 -> prelu -> out ----
// grid (782, NS). Phase 1: 8 groups of 32 lanes gather 64 rows into xs (stride 132,
// 16B-aligned ds_write_b128). Phase 2: standard 64-row GEMM from xs.
__global__ __launch_bounds__(256) void l2_fused_k(
    const unsigned short* __restrict__ ZhA, const int* __restrict__ offsA,
    const int* __restrict__ cntA, const int2* __restrict__ eeA,
    const float* __restrict__ dinvA, const float* __restrict__ W,
    const float* __restrict__ bias, const float* __restrict__ pa,
    float* __restrict__ out) {
  __shared__ float xs[64 * 132];
  __shared__ float ws[32 * 128];
  const int t = blockIdx.y;
  const int r0 = blockIdx.x * 64;
  const int tid = threadIdx.x;
  const unsigned short* Z = ZhA + (size_t)t * NN * D;

  // ---- phase 1: gather 64 aggregated rows into xs ----
  {
    const int grp = tid >> 5;   // 0..7
    const int lane = tid & 31;
    const int c = lane * 4;
    for (int it = 0; it < 8; it++) {
      const int row = grp * 8 + it;
      const int node = r0 + row;
      float ax = 0.f, ay = 0.f, az = 0.f, aw = 0.f;
      if (node < NN) {
        const int base = t * NN + node;
        const int st = offsA[base];
        const int len = cntA[base];
        int j = 0;
        for (; j + 4 <= len; j += 4) {
          int2 p0 = eeA[st + j];
          int2 p1 = eeA[st + j + 1];
          int2 p2 = eeA[st + j + 2];
          int2 p3 = eeA[st + j + 3];
          ushort4 v0 = *(const ushort4*)&Z[(size_t)p0.x * D + c];
          ushort4 v1 = *(const ushort4*)&Z[(size_t)p1.x * D + c];
          ushort4 v2 = *(const ushort4*)&Z[(size_t)p2.x * D + c];
          ushort4 v3 = *(const ushort4*)&Z[(size_t)p3.x * D + c];
          float w0 = __int_as_float(p0.y), w1 = __int_as_float(p1.y);
          float w2 = __int_as_float(p2.y), w3 = __int_as_float(p3.y);
          ax += w0 * bf2f(v0.x) + w1 * bf2f(v1.x) + w2 * bf2f(v2.x) + w3 * bf2f(v3.x);
          ay += w0 * bf2f(v0.y) + w1 * bf2f(v1.y) + w2 * bf2f(v2.y) + w3 * bf2f(v3.y);
          az += w0 * bf2f(v0.z) + w1 * bf2f(v1.z) + w2 * bf2f(v2.z) + w3 * bf2f(v3.z);
          aw += w0 * bf2f(v0.w) + w1 * bf2f(v1.w) + w2 * bf2f(v2.w) + w3 * bf2f(v3.w);
        }
        for (; j < len; j++) {
          int2 p = eeA[st + j];
          float w = __int_as_float(p.y);
          ushort4 v = *(const ushort4*)&Z[(size_t)p.x * D + c];
          ax += w * bf2f(v.x);
          ay += w * bf2f(v.y);
          az += w * bf2f(v.z);
          aw += w * bf2f(v.w);
        }
        float dv = dinvA[base];
        float d2 = dv * dv;
        ushort4 h = *(const ushort4*)&Z[(size_t)node * D + c];
        ax += d2 * bf2f(h.x);
        ay += d2 * bf2f(h.y);
        az += d2 * bf2f(h.z);
        aw += d2 * bf2f(h.w);
      }
      *(float4*)&xs[row * 132 + c] = make_float4(ax, ay, az, aw);
    }
  }

  // ---- phase 2: GEMM xs @ W + bias, prelu, store fp32 ----
  const int tx = tid & 15, ty = tid >> 4;
  float bv[8], av[8];
#pragma unroll
  for (int j = 0; j < 8; j++) {
    bv[j] = bias[tx * 8 + j];
    av[j] = pa[tx * 8 + j];
  }
  float acc[4][8];
#pragma unroll
  for (int i = 0; i < 4; i++)
#pragma unroll
    for (int j = 0; j < 8; j++) acc[i][j] = 0.f;

  for (int kc = 0; kc < 4; kc++) {
    __syncthreads();  // first iter: also closes phase 1
    for (int i = tid; i < 32 * 32; i += 256) {
      ((float4*)ws)[i] = ((const float4*)(W + kc * 32 * D))[i];
    }
    __syncthreads();
#pragma unroll 4
    for (int k2 = 0; k2 < 32; k2++) {
      const int k = kc * 32 + k2;
      float a[4];
#pragma unroll
      for (int j = 0; j < 4; j++) a[j] = xs[(ty * 4 + j) * 132 + k];
      float4 b0 = *(const float4*)&ws[k2 * 128 + tx * 8];
      float4 b1 = *(const float4*)&ws[k2 * 128 + tx * 8 + 4];
      float b[8] = {b0.x, b0.y, b0.z, b0.w, b1.x, b1.y, b1.z, b1.w};
#pragma unroll
      for (int i = 0; i < 4; i++)
#pragma unroll
        for (int j = 0; j < 8; j++) acc[i][j] += a[i] * b[j];
    }
  }
  float* outT = out + (size_t)t * NN * D;
#pragma unroll
  for (int i = 0; i < 4; i++) {
    int gr = r0 + ty * 4 + i;
    if (gr < NN) {
#pragma unroll
      for (int j = 0; j < 8; j++) {
        float v = acc[i][j] + bv[j];
        acc[i][j] = v > 0.f ? v : av[j] * v;
      }
      float4 o0 = make_float4(acc[i][0], acc[i][1], acc[i][2], acc[i][3]);
      float4 o1 = make_float4(acc[i][4], acc[i][5], acc[i][6], acc[i][7]);
      *(float4*)&outT[(size_t)gr * D + tx * 8] = o0;
      *(float4*)&outT[(size_t)gr * D + tx * 8 + 4] = o1;
    }
  }
}

// ---------------- launch ----------------

extern "C" void kernel_launch(void* const* d_in, const int* in_sizes, int n_in,
                              void* d_out, int out_size, void* d_ws, size_t ws_size,
                              hipStream_t stream) {
  const float* x = (const float*)d_in[0];
  const int* ei = (const int*)d_in[1];       // [4][2][NE] int32
  const float* ew = (const float*)d_in[2];   // [4][NE]
  const float* W0 = (const float*)d_in[3];
  const float* b0 = (const float*)d_in[4];
  const float* W1 = (const float*)d_in[5];
  const float* b1 = (const float*)d_in[6];
  const float* pa = (const float*)d_in[7];
  float* out = (float*)d_out;                // [4][NN][D] fp32

  // ws layout (d_ws assumed >=8B aligned; all segment sizes keep 8B alignment)
  ull* packedA = (ull*)d_ws;                              // NT ull      (1.6 MB)
  int2* eeA = (int2*)(packedA + NT);                      // NS*NE int2  (25.6 MB)
  int* posA = (int*)(eeA + (size_t)NS * NE);              // NS*NE int   (12.8 MB)
  float* dinvA = (float*)(posA + (size_t)NS * NE);        // NT f32
  int* cntA = (int*)(dinvA + NT);                         // NT
  int* offsA = cntA + NT;                                 // NT
  int* partial = offsA + NT;                              // 1024
  int* poffs = partial + 1024;                            // 1024
  unsigned short* H0h = (unsigned short*)(poffs + 1024);  // NN*D bf16 (12.8 MB)
  unsigned short* ZhA = H0h + (size_t)NN * D;             // NS*NN*D bf16 (51.2 MB)

  const int gGemm = (NN + 63) / 64;           // 782
  const int gEdge = (NE + 255) / 256;         // 3125
  const int gInit = (NT + 255) / 256;         // 782
  const int gGather = (NN * 32 + 255) / 256;  // 6250

  // H0h = bf16(x @ W0), shared across scales (independent of CSR build)
  gemm_plain_bf16out<<<gGemm, 256, 0, stream>>>(x, W0, H0h, NN);

  // batched CSR build for all 4 scales
  initp_k<<<gInit, 256, 0, stream>>>(packedA, NT);
  countpos_all_k<<<dim3(gEdge, NS), 256, 0, stream>>>(ei, ew, packedA, posA);
  unpack_scan_k<<<SB2, 256, 0, stream>>>(packedA, dinvA, cntA, partial);
  scan_top_k<<<1, 256, 0, stream>>>(partial, poffs, SB2);
  scan_write_k<<<SB2, 256, 0, stream>>>(cntA, poffs, offsA);
  fill_all_k<<<dim3(gEdge, NS), 256, 0, stream>>>(ei, ew, dinvA, offsA, posA, eeA);

  // layer 1 (all scales): ZhA[t] = bf16(prelu(Agg_t(H0h) + b0))
  gather1_all_k<<<dim3(gGather, NS), 256, 0, stream>>>(H0h, offsA, cntA, eeA,
                                                       dinvA, b0, pa, ZhA);
  // layer 2 (all scales, fused): out[t] = prelu(Agg_t(ZhA[t]) @ W1 + b1)
  l2_fused_k<<<dim3(gGemm, NS), 256, 0, stream>>>(ZhA, offsA, cntA, eeA, dinvA,
                                                  W1, b1, pa, out);
}